// Round 1
// 829.523 us; speedup vs baseline: 1.1734x; 1.1734x over previous
//
#include <hip/hip_runtime.h>
#include <hip/hip_bf16.h>

typedef unsigned short u16;
typedef __attribute__((ext_vector_type(8))) short bf16x8;   // 8 bf16 = 4 VGPRs (MFMA A/B frag)
typedef __attribute__((ext_vector_type(4))) float f32x4;    // MFMA C/D frag

__device__ __forceinline__ u16 f32_to_bf16(float f) {
  unsigned int x = __float_as_uint(f);
  x += 0x7fffu + ((x >> 16) & 1u);   // RNE
  return (u16)(x >> 16);
}

// ---------------------------------------------------------------------------
// prep 1: pn_sw = l2norm(prototypes) as bf16, swizzled chunk-major:
//   16B-unit index u = c*1024 + n*4 + q  holds pn[n][c*32 + q*8 + 0..7]
//   -> flat ushort idx = c*8192 + n*32 + q*8 + j
// A wave's GEMM1 B-frag load (16 protos x one q each) is a contiguous 1KB seg.
// ---------------------------------------------------------------------------
__global__ __launch_bounds__(256) void prep_pn_kernel(const float* __restrict__ P,
                                                      u16* __restrict__ pn_sw) {
  const int n = blockIdx.x;
  const int t = threadIdx.x;
  float v0 = P[n * 768 + t];
  float v1 = P[n * 768 + t + 256];
  float v2 = P[n * 768 + t + 512];
  float ss = v0 * v0 + v1 * v1 + v2 * v2;
#pragma unroll
  for (int m = 1; m < 64; m <<= 1) ss += __shfl_xor(ss, m, 64);
  __shared__ float wsum[4];
  if ((t & 63) == 0) wsum[t >> 6] = ss;
  __syncthreads();
  const float inv = 1.0f / fmaxf(sqrtf(wsum[0] + wsum[1] + wsum[2] + wsum[3]), 1e-12f);
  float vv[3] = {v0, v1, v2};
#pragma unroll
  for (int i = 0; i < 3; ++i) {
    int d = t + i * 256;
    int c = d >> 5, q = (d >> 3) & 3, j = d & 7;
    pn_sw[c * 8192 + n * 32 + q * 8 + j] = f32_to_bf16(vv[i] * inv);
  }
}

// ---------------------------------------------------------------------------
// prep 2: pw_sw = (P @ W^T)/256 as bf16, swizzled for GEMM2 B-frags:
//   flat ushort idx = ((s*768 + e)*4 + q)*8 + j  holds PW[e][k = s*32+q*8+j]
// ---------------------------------------------------------------------------
__global__ __launch_bounds__(256) void prep_pw_kernel(const float* __restrict__ P,
                                                      const float* __restrict__ W,
                                                      u16* __restrict__ pw_sw) {
  const int e0 = blockIdx.x * 4;
  const int t = threadIdx.x;
  __shared__ float Wl[4 * 768];
#pragma unroll
  for (int i = 0; i < 12; ++i) Wl[t + i * 256] = W[e0 * 768 + t + i * 256];
  __syncthreads();
  const float* prow = P + t * 768;  // thread t <-> prototype k = t
  float a0 = 0.f, a1 = 0.f, a2 = 0.f, a3 = 0.f;
  for (int d = 0; d < 768; d += 4) {
    float4 p = *(const float4*)(prow + d);
    a0 += p.x * Wl[d] + p.y * Wl[d + 1] + p.z * Wl[d + 2] + p.w * Wl[d + 3];
    a1 += p.x * Wl[768 + d] + p.y * Wl[768 + d + 1] + p.z * Wl[768 + d + 2] + p.w * Wl[768 + d + 3];
    a2 += p.x * Wl[1536 + d] + p.y * Wl[1536 + d + 1] + p.z * Wl[1536 + d + 2] + p.w * Wl[1536 + d + 3];
    a3 += p.x * Wl[2304 + d] + p.y * Wl[2304 + d + 1] + p.z * Wl[2304 + d + 2] + p.w * Wl[2304 + d + 3];
  }
  const int s = t >> 5, q = (t >> 3) & 3, j8 = t & 7;
  const float sc = 1.0f / 256.0f;
  float av[4] = {a0, a1, a2, a3};
#pragma unroll
  for (int j = 0; j < 4; ++j)
    pw_sw[((s * 768 + e0 + j) * 4 + q) * 8 + j8] = f32_to_bf16(av[j] * sc);
}

// ---------------------------------------------------------------------------
// fused main, v2 (latency-bound fixes):
//  - probL aliases xn (dead after GEMM1; 2 barriers separate last xn read from
//    first probL write) -> LDS 67.6 KB -> 50.8 KB -> 3 blocks/CU.
//  - GEMM1 re-tiled: wave w owns cols [w*64, w*64+64) x ALL 32 rows
//    -> 2 MFMA per global b-frag load (was 1), pn L2 traffic halved per block.
//  - depth-1 double-buffered b-frag prefetch in both GEMM inner loops.
// ---------------------------------------------------------------------------
__global__ __launch_bounds__(256, 3) void fused_kernel(const float* __restrict__ x,
                                                       const u16* __restrict__ pn_sw,
                                                       const u16* __restrict__ pw_sw,
                                                       const float* __restrict__ bias,
                                                       float* __restrict__ out) {
  __shared__ u16 xn[32 * 776];      // bf16 x (49664 B); probL (32x264, 16896 B) aliases it
  __shared__ float invn[32];
  __shared__ float rmax[4][32];
  __shared__ float rsum[4][32];
  u16* probL = xn;                  // alias: xn dead after GEMM1 (see barriers below)

  const int t = threadIdx.x;
  const int w = t >> 6;
  const int lane = t & 63;
  const int r = lane & 15, q = lane >> 4;
  const long row0 = (long)blockIdx.x * 32;

  // ---- phase 1: load x, per-row sumsq (fp32), store bf16 to LDS ----
  {
    const int row = t >> 3, s8 = t & 7;  // 8 threads per row
    const float4* xr = (const float4*)(x + (row0 + row) * 768);
    float ss = 0.f;
#pragma unroll
    for (int j = 0; j < 24; ++j) {
      float4 f = xr[s8 + j * 8];
      ss += f.x * f.x + f.y * f.y + f.z * f.z + f.w * f.w;
      ushort4 u;
      u.x = f32_to_bf16(f.x); u.y = f32_to_bf16(f.y);
      u.z = f32_to_bf16(f.z); u.w = f32_to_bf16(f.w);
      *(ushort4*)&xn[row * 776 + (s8 + j * 8) * 4] = u;
    }
    ss += __shfl_xor(ss, 1, 8);
    ss += __shfl_xor(ss, 2, 8);
    ss += __shfl_xor(ss, 4, 8);
    if (s8 == 0) invn[row] = 1.0f / fmaxf(sqrtf(ss), 1e-12f);
  }

  // ---- GEMM1 B pointers; prefetch c=0 frags before the barrier ----
  const u16* bP = pn_sw + (w * 64 + r) * 32 + q * 8;   // wave w -> protos [w*64, w*64+64)
  bf16x8 cb0 = *(const bf16x8*)(bP);
  bf16x8 cb1 = *(const bf16x8*)(bP + 512);
  bf16x8 cb2 = *(const bf16x8*)(bP + 1024);
  bf16x8 cb3 = *(const bf16x8*)(bP + 1536);
  __syncthreads();

  // ---- GEMM1: sim_raw[32x256] = x_bf16 . pn (norm folded into softmax) ----
  // wave w: 32 rows x 64 cols; accA = rows 0-15, accB = rows 16-31
  f32x4 accA[4], accB[4];
#pragma unroll
  for (int ct = 0; ct < 4; ++ct) {
    accA[ct] = f32x4{0.f, 0.f, 0.f, 0.f};
    accB[ct] = f32x4{0.f, 0.f, 0.f, 0.f};
  }
  const u16* aP0 = &xn[r * 776 + q * 8];
  const u16* aP1 = &xn[(16 + r) * 776 + q * 8];
#pragma unroll 4
  for (int c = 0; c < 23; ++c) {
    // prefetch next chunk's b-frags (consumed next iteration)
    bf16x8 nb0 = *(const bf16x8*)(bP + (c + 1) * 8192);
    bf16x8 nb1 = *(const bf16x8*)(bP + (c + 1) * 8192 + 512);
    bf16x8 nb2 = *(const bf16x8*)(bP + (c + 1) * 8192 + 1024);
    bf16x8 nb3 = *(const bf16x8*)(bP + (c + 1) * 8192 + 1536);
    bf16x8 a0 = *(const bf16x8*)(aP0 + c * 32);
    bf16x8 a1 = *(const bf16x8*)(aP1 + c * 32);
    accA[0] = __builtin_amdgcn_mfma_f32_16x16x32_bf16(a0, cb0, accA[0], 0, 0, 0);
    accB[0] = __builtin_amdgcn_mfma_f32_16x16x32_bf16(a1, cb0, accB[0], 0, 0, 0);
    accA[1] = __builtin_amdgcn_mfma_f32_16x16x32_bf16(a0, cb1, accA[1], 0, 0, 0);
    accB[1] = __builtin_amdgcn_mfma_f32_16x16x32_bf16(a1, cb1, accB[1], 0, 0, 0);
    accA[2] = __builtin_amdgcn_mfma_f32_16x16x32_bf16(a0, cb2, accA[2], 0, 0, 0);
    accB[2] = __builtin_amdgcn_mfma_f32_16x16x32_bf16(a1, cb2, accB[2], 0, 0, 0);
    accA[3] = __builtin_amdgcn_mfma_f32_16x16x32_bf16(a0, cb3, accA[3], 0, 0, 0);
    accB[3] = __builtin_amdgcn_mfma_f32_16x16x32_bf16(a1, cb3, accB[3], 0, 0, 0);
    cb0 = nb0; cb1 = nb1; cb2 = nb2; cb3 = nb3;
  }
  {  // tail c = 23
    bf16x8 a0 = *(const bf16x8*)(aP0 + 23 * 32);
    bf16x8 a1 = *(const bf16x8*)(aP1 + 23 * 32);
    accA[0] = __builtin_amdgcn_mfma_f32_16x16x32_bf16(a0, cb0, accA[0], 0, 0, 0);
    accB[0] = __builtin_amdgcn_mfma_f32_16x16x32_bf16(a1, cb0, accB[0], 0, 0, 0);
    accA[1] = __builtin_amdgcn_mfma_f32_16x16x32_bf16(a0, cb1, accA[1], 0, 0, 0);
    accB[1] = __builtin_amdgcn_mfma_f32_16x16x32_bf16(a1, cb1, accB[1], 0, 0, 0);
    accA[2] = __builtin_amdgcn_mfma_f32_16x16x32_bf16(a0, cb2, accA[2], 0, 0, 0);
    accB[2] = __builtin_amdgcn_mfma_f32_16x16x32_bf16(a1, cb2, accB[2], 0, 0, 0);
    accA[3] = __builtin_amdgcn_mfma_f32_16x16x32_bf16(a0, cb3, accA[3], 0, 0, 0);
    accB[3] = __builtin_amdgcn_mfma_f32_16x16x32_bf16(a1, cb3, accB[3], 0, 0, 0);
  }

  // ---- softmax over 256 per row: e = exp(inv*(s - smax)); p = e/sum ----
  // C layout: col = lane&15 (= r), row = q*4 + i  (verified m89/m91)
  const int rbA = q * 4;
#pragma unroll
  for (int i = 0; i < 4; ++i) {
    float mA = fmaxf(fmaxf(accA[0][i], accA[1][i]), fmaxf(accA[2][i], accA[3][i]));
    float mB = fmaxf(fmaxf(accB[0][i], accB[1][i]), fmaxf(accB[2][i], accB[3][i]));
    mA = fmaxf(mA, __shfl_xor(mA, 1, 16));
    mA = fmaxf(mA, __shfl_xor(mA, 2, 16));
    mA = fmaxf(mA, __shfl_xor(mA, 4, 16));
    mA = fmaxf(mA, __shfl_xor(mA, 8, 16));
    mB = fmaxf(mB, __shfl_xor(mB, 1, 16));
    mB = fmaxf(mB, __shfl_xor(mB, 2, 16));
    mB = fmaxf(mB, __shfl_xor(mB, 4, 16));
    mB = fmaxf(mB, __shfl_xor(mB, 8, 16));
    if (r == 0) {
      rmax[w][rbA + i] = mA;
      rmax[w][16 + rbA + i] = mB;
    }
  }
  __syncthreads();   // <- all xn reads complete at this barrier
#pragma unroll
  for (int i = 0; i < 4; ++i) {
    const int rowA = rbA + i, rowB = 16 + rbA + i;
    const float mxA = fmaxf(fmaxf(rmax[0][rowA], rmax[1][rowA]), fmaxf(rmax[2][rowA], rmax[3][rowA]));
    const float mxB = fmaxf(fmaxf(rmax[0][rowB], rmax[1][rowB]), fmaxf(rmax[2][rowB], rmax[3][rowB]));
    const float ivA = invn[rowA], ivB = invn[rowB];
    float sA = 0.f, sB = 0.f;
#pragma unroll
    for (int ct = 0; ct < 4; ++ct) {
      float eA = __expf((accA[ct][i] - mxA) * ivA);
      float eB = __expf((accB[ct][i] - mxB) * ivB);
      accA[ct][i] = eA; accB[ct][i] = eB;
      sA += eA; sB += eB;
    }
    sA += __shfl_xor(sA, 1, 16);
    sA += __shfl_xor(sA, 2, 16);
    sA += __shfl_xor(sA, 4, 16);
    sA += __shfl_xor(sA, 8, 16);
    sB += __shfl_xor(sB, 1, 16);
    sB += __shfl_xor(sB, 2, 16);
    sB += __shfl_xor(sB, 4, 16);
    sB += __shfl_xor(sB, 8, 16);
    if (r == 0) {
      rsum[w][rowA] = sA;
      rsum[w][rowB] = sB;
    }
  }
  __syncthreads();
#pragma unroll
  for (int i = 0; i < 4; ++i) {
    const int rowA = rbA + i, rowB = 16 + rbA + i;
    const float isA = 1.0f / (rsum[0][rowA] + rsum[1][rowA] + rsum[2][rowA] + rsum[3][rowA]);
    const float isB = 1.0f / (rsum[0][rowB] + rsum[1][rowB] + rsum[2][rowB] + rsum[3][rowB]);
#pragma unroll
    for (int ct = 0; ct < 4; ++ct) {
      probL[rowA * 264 + w * 64 + ct * 16 + r] = f32_to_bf16(accA[ct][i] * isA);
      probL[rowB * 264 + w * 64 + ct * 16 + r] = f32_to_bf16(accB[ct][i] * isB);
    }
  }
  __syncthreads();

  // ---- GEMM2: out[32x768] = prob @ PW + b ; wave w owns cols [192w,192w+192) ----
  const u16* aQ0 = &probL[r * 264 + q * 8];
  const u16* aQ1 = &probL[(16 + r) * 264 + q * 8];
  for (int pass = 0; pass < 3; ++pass) {
    const int e0 = w * 192 + pass * 64;
    bf16x8 bb0 = *(const bf16x8*)(pw_sw + ((e0 + r) * 4 + q) * 8);
    bf16x8 bb1 = *(const bf16x8*)(pw_sw + ((e0 + 16 + r) * 4 + q) * 8);
    bf16x8 bb2 = *(const bf16x8*)(pw_sw + ((e0 + 32 + r) * 4 + q) * 8);
    bf16x8 bb3 = *(const bf16x8*)(pw_sw + ((e0 + 48 + r) * 4 + q) * 8);
    f32x4 o0[4], o1[4];
#pragma unroll
    for (int ct = 0; ct < 4; ++ct) {
      o0[ct] = f32x4{0.f, 0.f, 0.f, 0.f};
      o1[ct] = f32x4{0.f, 0.f, 0.f, 0.f};
    }
#pragma unroll
    for (int s = 0; s < 8; ++s) {
      bf16x8 a0 = *(const bf16x8*)(aQ0 + s * 32);
      bf16x8 a1 = *(const bf16x8*)(aQ1 + s * 32);
      bf16x8 n0, n1, n2, n3;
      if (s < 7) {
        n0 = *(const bf16x8*)(pw_sw + (((s + 1) * 768 + e0 + r) * 4 + q) * 8);
        n1 = *(const bf16x8*)(pw_sw + (((s + 1) * 768 + e0 + 16 + r) * 4 + q) * 8);
        n2 = *(const bf16x8*)(pw_sw + (((s + 1) * 768 + e0 + 32 + r) * 4 + q) * 8);
        n3 = *(const bf16x8*)(pw_sw + (((s + 1) * 768 + e0 + 48 + r) * 4 + q) * 8);
      }
      o0[0] = __builtin_amdgcn_mfma_f32_16x16x32_bf16(a0, bb0, o0[0], 0, 0, 0);
      o1[0] = __builtin_amdgcn_mfma_f32_16x16x32_bf16(a1, bb0, o1[0], 0, 0, 0);
      o0[1] = __builtin_amdgcn_mfma_f32_16x16x32_bf16(a0, bb1, o0[1], 0, 0, 0);
      o1[1] = __builtin_amdgcn_mfma_f32_16x16x32_bf16(a1, bb1, o1[1], 0, 0, 0);
      o0[2] = __builtin_amdgcn_mfma_f32_16x16x32_bf16(a0, bb2, o0[2], 0, 0, 0);
      o1[2] = __builtin_amdgcn_mfma_f32_16x16x32_bf16(a1, bb2, o1[2], 0, 0, 0);
      o0[3] = __builtin_amdgcn_mfma_f32_16x16x32_bf16(a0, bb3, o0[3], 0, 0, 0);
      o1[3] = __builtin_amdgcn_mfma_f32_16x16x32_bf16(a1, bb3, o1[3], 0, 0, 0);
      if (s < 7) { bb0 = n0; bb1 = n1; bb2 = n2; bb3 = n3; }
    }
#pragma unroll
    for (int ct = 0; ct < 4; ++ct) {
      const int e = e0 + ct * 16 + r;
      const float bv = bias[e];
#pragma unroll
      for (int i = 0; i < 4; ++i) {
        out[(row0 + q * 4 + i) * 768 + e] = o0[ct][i] + bv;
        out[(row0 + 16 + q * 4 + i) * 768 + e] = o1[ct][i] + bv;
      }
    }
  }
}

extern "C" void kernel_launch(void* const* d_in, const int* in_sizes, int n_in,
                              void* d_out, int out_size, void* d_ws, size_t ws_size,
                              hipStream_t stream) {
  const float* x = (const float*)d_in[0];      // (8,16384,768)
  const float* P = (const float*)d_in[1];      // (256,768)
  const float* W = (const float*)d_in[2];      // (768,768)
  const float* b = (const float*)d_in[3];      // (768,)
  float* out = (float*)d_out;                  // (8,16384,768) fp32

  u16* pn_sw = (u16*)d_ws;                     // 393216 B
  u16* pw_sw = (u16*)d_ws + 256 * 768;         // 393216 B  (needs ws >= 786432 B)

  hipLaunchKernelGGL(prep_pn_kernel, dim3(256), dim3(256), 0, stream, P, pn_sw);
  hipLaunchKernelGGL(prep_pw_kernel, dim3(192), dim3(256), 0, stream, P, W, pw_sw);
  hipLaunchKernelGGL(fused_kernel, dim3(4096), dim3(256), 0, stream, x, pn_sw, pw_sw, b, out);
}